// Round 5
// baseline (636.673 us; speedup 1.0000x reference)
//
#include <hip/hip_runtime.h>

// GCN forward on MI355X.
// Pipeline per call (all on `stream`, graph-capture safe):
//   memset(counts) -> count in-degrees -> 3-phase multi-block scan
//   (partial sums -> scan partials -> apply; also emits dinv)
//   -> fill CSR (atomic cursor on offsets; offsets become END pointers)
//   -> per layer: [gemm: g = dinv .* (h @ W)] then [aggregate: XCD-sliced
//      CSR gather-sum, + self, * dinv, + bias, relu]
//   -> fused pool+FC head (batch sorted -> binary-search ranges, no atomics).
// Norm factorization: out[c] = dinv[c]*(sum_{src->c} g[src] + g[c]) + b,
// with g = dinv .* (h@W). No per-edge multiplies, no float atomics anywhere.
// R2: single-block scan was 124us -> multi-block scan.
// R3: aggregate gathered 512B rows from a 25.6MB buffer; per-XCD L2 (4MiB)
//     spilled half the traffic to fabric (FETCH 143MB @2.4TB/s). Now sliced:
//     slice = blockIdx % 8 -> XCD round-robin puts a 3.2MB (16-col) slice of G
//     resident in each XCD's L2; csr/H marked nontemporal to protect it.
// R4: __builtin_nontemporal_store needs a clang ext_vector_type, not HIP float4.

#define K_IN 128

typedef float f32x4 __attribute__((ext_vector_type(4)));

static inline size_t align256(size_t x) { return (x + 255) & ~(size_t)255; }

__global__ void count_edges(const int* __restrict__ col, int E, int* __restrict__ cnt) {
    int e = blockIdx.x * blockDim.x + threadIdx.x;
    if (e < E) atomicAdd(&cnt[col[e]], 1);
}

// Phase 1: per-block (256-elt chunk) sums of cnt.
__global__ __launch_bounds__(256) void scan_part_sums(const int* __restrict__ cnt,
                                                      int N, int* __restrict__ part) {
    __shared__ int red[256];
    int t = threadIdx.x;
    int i = blockIdx.x * 256 + t;
    red[t] = (i < N) ? cnt[i] : 0;
    __syncthreads();
    for (int s = 128; s > 0; s >>= 1) {
        if (t < s) red[t] += red[t + s];
        __syncthreads();
    }
    if (t == 0) part[blockIdx.x] = red[0];
}

// Phase 2: single block exclusive-scan of nb partials (nb <= 1024).
__global__ __launch_bounds__(1024) void scan_partials(int* __restrict__ part, int nb) {
    __shared__ int sh[1024];
    int t = threadIdx.x;
    int v = (t < nb) ? part[t] : 0;
    sh[t] = v;
    __syncthreads();
    int incl = v;
    for (int s = 1; s < 1024; s <<= 1) {
        int add = (t >= s) ? sh[t - s] : 0;
        __syncthreads();
        incl += add;
        sh[t] = incl;
        __syncthreads();
    }
    if (t < nb) part[t] = incl - v;
}

// Phase 3: block-local exclusive scan + block prefix; cnt->offsets in place,
// emits dinv[i] = rsqrt(deg_in + 1).
__global__ __launch_bounds__(256) void scan_apply(int* __restrict__ off,
                                                  float* __restrict__ dinv,
                                                  const int* __restrict__ part, int N) {
    __shared__ int sh[256];
    int t = threadIdx.x;
    int i = blockIdx.x * 256 + t;
    int c = (i < N) ? off[i] : 0;
    sh[t] = c;
    __syncthreads();
    int incl = c;
    for (int s = 1; s < 256; s <<= 1) {
        int add = (t >= s) ? sh[t - s] : 0;
        __syncthreads();
        incl += add;
        sh[t] = incl;
        __syncthreads();
    }
    if (i < N) {
        off[i] = part[blockIdx.x] + incl - c;
        dinv[i] = rsqrtf((float)(c + 1));
    }
}

// After this kernel, off[i] == end offset of node i (== start of node i+1).
__global__ void fill_csr(const int* __restrict__ rowi, const int* __restrict__ coli,
                         int E, int* __restrict__ off, int* __restrict__ csr) {
    int e = blockIdx.x * blockDim.x + threadIdx.x;
    if (e < E) {
        int c = coli[e];
        int p = atomicAdd(&off[c], 1);
        csr[p] = rowi[e];
    }
}

// G = dinv .* (X @ W).  X: [N,128], W: [128,COLS], G: [N,COLS]. fp32 LDS-tiled.
template <int COLS>
__global__ __launch_bounds__(256) void gemm_dinv(const float* __restrict__ X,
                                                 const float* __restrict__ W,
                                                 const float* __restrict__ dinv,
                                                 float* __restrict__ G, int N) {
    constexpr int CG = COLS / 4;       // col groups of 4
    constexpr int RG = 256 / CG;       // row groups
    constexpr int ROWS = RG * 4;       // rows per block (32 or 64)
    constexpr int BK = 64;
    constexpr int PAD = 4;             // keep 16B alignment for b128 reads
    __shared__ float Ws[BK][COLS];
    __shared__ float Xs[BK][ROWS + PAD];  // X tile transposed: Xs[k][r]

    int t = threadIdx.x;
    int rowBase = blockIdx.x * ROWS;
    float acc[4][4] = {};

    for (int kt = 0; kt < K_IN; kt += BK) {
        // stage W tile (coalesced float4)
        for (int i = t; i < BK * (COLS / 4); i += 256) {
            int c4 = i % (COLS / 4), k = i / (COLS / 4);
            float4 v = *(const float4*)(W + (kt + k) * COLS + c4 * 4);
            *(float4*)&Ws[k][c4 * 4] = v;
        }
        // stage X tile, transposed (coalesced float4 read, scalar LDS writes)
        for (int i = t; i < ROWS * (BK / 4); i += 256) {
            int k4 = i % (BK / 4), r = i / (BK / 4);
            int row = rowBase + r;
            float4 v = make_float4(0.f, 0.f, 0.f, 0.f);
            if (row < N) v = *(const float4*)(X + row * K_IN + kt + k4 * 4);
            Xs[k4 * 4 + 0][r] = v.x;
            Xs[k4 * 4 + 1][r] = v.y;
            Xs[k4 * 4 + 2][r] = v.z;
            Xs[k4 * 4 + 3][r] = v.w;
        }
        __syncthreads();
        int c0 = (t % CG) * 4, r0 = (t / CG) * 4;
#pragma unroll
        for (int k = 0; k < BK; k++) {
            float4 xv = *(const float4*)&Xs[k][r0];
            float4 wv = *(const float4*)&Ws[k][c0];
            acc[0][0] += xv.x * wv.x; acc[0][1] += xv.x * wv.y;
            acc[0][2] += xv.x * wv.z; acc[0][3] += xv.x * wv.w;
            acc[1][0] += xv.y * wv.x; acc[1][1] += xv.y * wv.y;
            acc[1][2] += xv.y * wv.z; acc[1][3] += xv.y * wv.w;
            acc[2][0] += xv.z * wv.x; acc[2][1] += xv.z * wv.y;
            acc[2][2] += xv.z * wv.z; acc[2][3] += xv.z * wv.w;
            acc[3][0] += xv.w * wv.x; acc[3][1] += xv.w * wv.y;
            acc[3][2] += xv.w * wv.z; acc[3][3] += xv.w * wv.w;
        }
        __syncthreads();
    }
    int c0 = (t % CG) * 4, r0 = (t / CG) * 4;
#pragma unroll
    for (int i = 0; i < 4; i++) {
        int row = rowBase + r0 + i;
        if (row < N) {
            float d = dinv[row];
            float4 o = make_float4(d * acc[i][0], d * acc[i][1],
                                   d * acc[i][2], d * acc[i][3]);
            *(float4*)(G + row * COLS + c0) = o;
        }
    }
}

// XCD-sliced aggregate: grid = nchunks * NSLICE, slice = blockIdx % NSLICE so
// round-robin dispatch pins slice s to XCD s (mod). Each block: 64 nodes x
// 4 lanes; lane owns a float4 of a 16-col slice. The slice of G (N*16*4 =
// 3.2MB) stays resident in that XCD's 4MiB L2; gathers hit L2 instead of
// fabric. csr/H are streaming -> nontemporal.
// H[i] = relu(dinv[i]*(sum_{p} G[csr[p]] + G[i]) + bias)
template <int F, int NSLICE>
__global__ __launch_bounds__(256) void aggregate_sliced(
        const float* __restrict__ G, const int* __restrict__ csr,
        const int* __restrict__ offEnd, const float* __restrict__ dinv,
        const float* __restrict__ bias, float* __restrict__ H, int N) {
    int slice = blockIdx.x % NSLICE;
    int chunk = blockIdx.x / NSLICE;
    int t = threadIdx.x;
    int node = chunk * 64 + (t >> 2);
    if (node >= N) return;
    int col = slice * 16 + (t & 3) * 4;
    const float* __restrict__ Gc = G + col;
    f32x4 acc = *(const f32x4*)(Gc + (size_t)node * F);  // self-loop term
    int start = node ? offEnd[node - 1] : 0;
    int end = offEnd[node];
    for (int p = start; p < end; p++) {
        int s = __builtin_nontemporal_load(csr + p);
        f32x4 v = *(const f32x4*)(Gc + (size_t)s * F);
        acc += v;
    }
    float d = dinv[node];
    f32x4 o;
    o.x = fmaxf(d * acc.x + bias[col + 0], 0.f);
    o.y = fmaxf(d * acc.y + bias[col + 1], 0.f);
    o.z = fmaxf(d * acc.z + bias[col + 2], 0.f);
    o.w = fmaxf(d * acc.w + bias[col + 3], 0.f);
    __builtin_nontemporal_store(o, (f32x4*)(H + (size_t)node * F + col));
}

__device__ inline int lower_bound_i(const int* __restrict__ a, int n, int key) {
    int lo = 0, hi = n;
    while (lo < hi) {
        int mid = (lo + hi) >> 1;
        if (a[mid] < key) lo = mid + 1; else hi = mid;
    }
    return lo;
}

// Fused mean-pool + FC head. batch is SORTED, so graph g's nodes are the
// contiguous range [lower_bound(g), lower_bound(g+1)). One block per graph,
// 256 threads = 4 waves; wave w strides rows, lane = feature. No atomics.
__global__ __launch_bounds__(256) void pool_head(
        const float* __restrict__ H, const int* __restrict__ batch, int N,
        const float* __restrict__ Wf1, const float* __restrict__ bf1,
        const float* __restrict__ Wf2, const float* __restrict__ bf2,
        float* __restrict__ out) {
    __shared__ float red[4][64];
    __shared__ float pooled[64];
    __shared__ float f1[32];
    int g = blockIdx.x;
    int t = threadIdx.x;
    int wave = t >> 6, lane = t & 63;
    int lo = lower_bound_i(batch, N, g);
    int hi = lower_bound_i(batch, N, g + 1);
    float acc = 0.f;
    for (int i = lo + wave; i < hi; i += 4) acc += H[i * 64 + lane];
    red[wave][lane] = acc;
    __syncthreads();
    if (t < 64) {
        float c = fmaxf((float)(hi - lo), 1.0f);
        pooled[t] = (red[0][t] + red[1][t] + red[2][t] + red[3][t]) / c;
    }
    __syncthreads();
    if (t < 32) {
        float s = bf1[t];
        for (int k = 0; k < 64; k++) s += pooled[k] * Wf1[k * 32 + t];
        f1[t] = fmaxf(s, 0.f);
    }
    __syncthreads();
    if (t < 10) {
        float s = bf2[t];
        for (int k = 0; k < 32; k++) s += f1[k] * Wf2[k * 10 + t];
        out[g * 10 + t] = s;
    }
}

extern "C" void kernel_launch(void* const* d_in, const int* in_sizes, int n_in,
                              void* d_out, int out_size, void* d_ws, size_t ws_size,
                              hipStream_t stream) {
    const float* x    = (const float*)d_in[0];
    const int*   ei   = (const int*)d_in[1];   // [2,E] flat: [0..E)=src, [E..2E)=dst
    const int*   batch= (const int*)d_in[2];
    const float* W1 = (const float*)d_in[3];
    const float* b1 = (const float*)d_in[4];
    const float* W2 = (const float*)d_in[5];
    const float* b2 = (const float*)d_in[6];
    const float* W3 = (const float*)d_in[7];
    const float* b3 = (const float*)d_in[8];
    const float* Wf1 = (const float*)d_in[9];
    const float* bf1 = (const float*)d_in[10];
    const float* Wf2 = (const float*)d_in[11];
    const float* bf2 = (const float*)d_in[12];

    const int N = in_sizes[0] / 128;
    const int E = in_sizes[1] / 2;
    const int nb = (N + 255) / 256;   // scan blocks (<=1024 supported)

    // workspace layout
    char* w = (char*)d_ws;
    int*   off  = (int*)w;    w += align256((size_t)N * 4);
    float* dinv = (float*)w;  w += align256((size_t)N * 4);
    int*   part = (int*)w;    w += align256((size_t)1024 * 4);
    int*   csr  = (int*)w;    w += align256((size_t)E * 4);
    float* buf0 = (float*)w;  w += align256((size_t)N * 128 * 4);
    float* buf1 = (float*)w;  w += align256((size_t)N * 128 * 4);
    (void)ws_size; (void)n_in; (void)out_size;

    (void)hipMemsetAsync(off, 0, (size_t)N * 4, stream);

    int eb = (E + 255) / 256;
    count_edges<<<eb, 256, 0, stream>>>(ei + E, E, off);
    scan_part_sums<<<nb, 256, 0, stream>>>(off, N, part);
    scan_partials<<<1, 1024, 0, stream>>>(part, nb);
    scan_apply<<<nb, 256, 0, stream>>>(off, dinv, part, N);
    fill_csr<<<eb, 256, 0, stream>>>(ei, ei + E, E, off, csr);

    int nchunk = (N + 63) / 64;
    // layer 1: x[ N,128 ] -> h1 (buf1)
    gemm_dinv<128><<<(N + 31) / 32, 256, 0, stream>>>(x, W1, dinv, buf0, N);
    aggregate_sliced<128, 8><<<nchunk * 8, 256, 0, stream>>>(buf0, csr, off, dinv, b1, buf1, N);
    // layer 2
    gemm_dinv<128><<<(N + 31) / 32, 256, 0, stream>>>(buf1, W2, dinv, buf0, N);
    aggregate_sliced<128, 8><<<nchunk * 8, 256, 0, stream>>>(buf0, csr, off, dinv, b2, buf1, N);
    // layer 3 (128 -> 64)
    gemm_dinv<64><<<(N + 63) / 64, 256, 0, stream>>>(buf1, W3, dinv, buf0, N);
    aggregate_sliced<64, 4><<<nchunk * 4, 256, 0, stream>>>(buf0, csr, off, dinv, b3, buf1, N);

    pool_head<<<64, 256, 0, stream>>>(buf1, batch, N, Wf1, bf1, Wf2, bf2,
                                      (float*)d_out);
}

// Round 6
// 427.831 us; speedup vs baseline: 1.4881x; 1.4881x over previous
//
#include <hip/hip_runtime.h>

// GCN forward on MI355X.
// Pipeline per call (all on `stream`, graph-capture safe):
//   memset(counts) -> count in-degrees -> 3-phase multi-block scan
//   (partial sums -> scan partials -> apply; also emits dinv)
//   -> fill CSR (atomic cursor on offsets; offsets become END pointers)
//   -> per layer: [gemm: g = dinv .* (h @ W)] then [aggregate: CSR gather-sum
//      with 4-way MLP unroll, + self, * dinv, + bias, relu]
//   -> fused pool+FC head (batch sorted -> binary-search ranges, no atomics).
// Norm factorization: out[c] = dinv[c]*(sum_{src->c} g[src] + g[c]) + b,
// with g = dinv .* (h@W). No per-edge multiplies, no float atomics anywhere.
// R2: single-block scan was 124us -> multi-block scan.
// R5: XCD-slicing REGRESSED (FETCH 143->261MB: 64B slices split 128B lines
//     across XCDs; L2 residency didn't materialize). Reverted to R3 shape.
// R6: gather loop was 1 outstanding 512B row per wave (latency-bound,
//     VALUBusy 12%, fetch BW only 2TB/s); 4-way unroll for MLP.

#define K_IN 128

static inline size_t align256(size_t x) { return (x + 255) & ~(size_t)255; }

__global__ void count_edges(const int* __restrict__ col, int E, int* __restrict__ cnt) {
    int e = blockIdx.x * blockDim.x + threadIdx.x;
    if (e < E) atomicAdd(&cnt[col[e]], 1);
}

// Phase 1: per-block (256-elt chunk) sums of cnt.
__global__ __launch_bounds__(256) void scan_part_sums(const int* __restrict__ cnt,
                                                      int N, int* __restrict__ part) {
    __shared__ int red[256];
    int t = threadIdx.x;
    int i = blockIdx.x * 256 + t;
    red[t] = (i < N) ? cnt[i] : 0;
    __syncthreads();
    for (int s = 128; s > 0; s >>= 1) {
        if (t < s) red[t] += red[t + s];
        __syncthreads();
    }
    if (t == 0) part[blockIdx.x] = red[0];
}

// Phase 2: single block exclusive-scan of nb partials (nb <= 1024).
__global__ __launch_bounds__(1024) void scan_partials(int* __restrict__ part, int nb) {
    __shared__ int sh[1024];
    int t = threadIdx.x;
    int v = (t < nb) ? part[t] : 0;
    sh[t] = v;
    __syncthreads();
    int incl = v;
    for (int s = 1; s < 1024; s <<= 1) {
        int add = (t >= s) ? sh[t - s] : 0;
        __syncthreads();
        incl += add;
        sh[t] = incl;
        __syncthreads();
    }
    if (t < nb) part[t] = incl - v;
}

// Phase 3: block-local exclusive scan + block prefix; cnt->offsets in place,
// emits dinv[i] = rsqrt(deg_in + 1).
__global__ __launch_bounds__(256) void scan_apply(int* __restrict__ off,
                                                  float* __restrict__ dinv,
                                                  const int* __restrict__ part, int N) {
    __shared__ int sh[256];
    int t = threadIdx.x;
    int i = blockIdx.x * 256 + t;
    int c = (i < N) ? off[i] : 0;
    sh[t] = c;
    __syncthreads();
    int incl = c;
    for (int s = 1; s < 256; s <<= 1) {
        int add = (t >= s) ? sh[t - s] : 0;
        __syncthreads();
        incl += add;
        sh[t] = incl;
        __syncthreads();
    }
    if (i < N) {
        off[i] = part[blockIdx.x] + incl - c;
        dinv[i] = rsqrtf((float)(c + 1));
    }
}

// After this kernel, off[i] == end offset of node i (== start of node i+1).
__global__ void fill_csr(const int* __restrict__ rowi, const int* __restrict__ coli,
                         int E, int* __restrict__ off, int* __restrict__ csr) {
    int e = blockIdx.x * blockDim.x + threadIdx.x;
    if (e < E) {
        int c = coli[e];
        int p = atomicAdd(&off[c], 1);
        csr[p] = rowi[e];
    }
}

// G = dinv .* (X @ W).  X: [N,128], W: [128,COLS], G: [N,COLS]. fp32 LDS-tiled.
template <int COLS>
__global__ __launch_bounds__(256) void gemm_dinv(const float* __restrict__ X,
                                                 const float* __restrict__ W,
                                                 const float* __restrict__ dinv,
                                                 float* __restrict__ G, int N) {
    constexpr int CG = COLS / 4;       // col groups of 4
    constexpr int RG = 256 / CG;       // row groups
    constexpr int ROWS = RG * 4;       // rows per block (32 or 64)
    constexpr int BK = 64;
    constexpr int PAD = 4;             // keep 16B alignment for b128 reads
    __shared__ float Ws[BK][COLS];
    __shared__ float Xs[BK][ROWS + PAD];  // X tile transposed: Xs[k][r]

    int t = threadIdx.x;
    int rowBase = blockIdx.x * ROWS;
    float acc[4][4] = {};

    for (int kt = 0; kt < K_IN; kt += BK) {
        // stage W tile (coalesced float4)
        for (int i = t; i < BK * (COLS / 4); i += 256) {
            int c4 = i % (COLS / 4), k = i / (COLS / 4);
            float4 v = *(const float4*)(W + (kt + k) * COLS + c4 * 4);
            *(float4*)&Ws[k][c4 * 4] = v;
        }
        // stage X tile, transposed (coalesced float4 read, scalar LDS writes)
        for (int i = t; i < ROWS * (BK / 4); i += 256) {
            int k4 = i % (BK / 4), r = i / (BK / 4);
            int row = rowBase + r;
            float4 v = make_float4(0.f, 0.f, 0.f, 0.f);
            if (row < N) v = *(const float4*)(X + row * K_IN + kt + k4 * 4);
            Xs[k4 * 4 + 0][r] = v.x;
            Xs[k4 * 4 + 1][r] = v.y;
            Xs[k4 * 4 + 2][r] = v.z;
            Xs[k4 * 4 + 3][r] = v.w;
        }
        __syncthreads();
        int c0 = (t % CG) * 4, r0 = (t / CG) * 4;
#pragma unroll
        for (int k = 0; k < BK; k++) {
            float4 xv = *(const float4*)&Xs[k][r0];
            float4 wv = *(const float4*)&Ws[k][c0];
            acc[0][0] += xv.x * wv.x; acc[0][1] += xv.x * wv.y;
            acc[0][2] += xv.x * wv.z; acc[0][3] += xv.x * wv.w;
            acc[1][0] += xv.y * wv.x; acc[1][1] += xv.y * wv.y;
            acc[1][2] += xv.y * wv.z; acc[1][3] += xv.y * wv.w;
            acc[2][0] += xv.z * wv.x; acc[2][1] += xv.z * wv.y;
            acc[2][2] += xv.z * wv.z; acc[2][3] += xv.z * wv.w;
            acc[3][0] += xv.w * wv.x; acc[3][1] += xv.w * wv.y;
            acc[3][2] += xv.w * wv.z; acc[3][3] += xv.w * wv.w;
        }
        __syncthreads();
    }
    int c0 = (t % CG) * 4, r0 = (t / CG) * 4;
#pragma unroll
    for (int i = 0; i < 4; i++) {
        int row = rowBase + r0 + i;
        if (row < N) {
            float d = dinv[row];
            float4 o = make_float4(d * acc[i][0], d * acc[i][1],
                                   d * acc[i][2], d * acc[i][3]);
            *(float4*)(G + row * COLS + c0) = o;
        }
    }
}

// One wave per node, lane owns a float2 (F=128) or float (F=64) of the row.
// Edge loop unrolled x4: batch 4 csr index loads, then 4 independent row
// gathers in flight (MLP), accumulate into 2 partial sums.
// H[i] = relu(dinv[i]*(sum_{p} G[csr[p]] + G[i]) + bias)
template <int F>
__global__ void aggregate(const float* __restrict__ G, const int* __restrict__ csr,
                          const int* __restrict__ offEnd, const float* __restrict__ dinv,
                          const float* __restrict__ bias, float* __restrict__ H, int N) {
    int gid = blockIdx.x * blockDim.x + threadIdx.x;
    int node = gid >> 6;
    int lane = gid & 63;
    if (node >= N) return;
    int start = node ? offEnd[node - 1] : 0;
    int end = offEnd[node];
    if (F == 128) {
        int o = lane * 2;
        const float* __restrict__ Gc = G + o;
        float2 acc0 = *(const float2*)(Gc + (size_t)node * 128);  // self-loop
        float2 acc1 = make_float2(0.f, 0.f);
        int p = start;
        for (; p + 4 <= end; p += 4) {
            int s0 = csr[p + 0];
            int s1 = csr[p + 1];
            int s2 = csr[p + 2];
            int s3 = csr[p + 3];
            float2 v0 = *(const float2*)(Gc + (size_t)s0 * 128);
            float2 v1 = *(const float2*)(Gc + (size_t)s1 * 128);
            float2 v2 = *(const float2*)(Gc + (size_t)s2 * 128);
            float2 v3 = *(const float2*)(Gc + (size_t)s3 * 128);
            acc0.x += v0.x; acc0.y += v0.y;
            acc1.x += v1.x; acc1.y += v1.y;
            acc0.x += v2.x; acc0.y += v2.y;
            acc1.x += v3.x; acc1.y += v3.y;
        }
        for (; p < end; p++) {
            int s = csr[p];
            float2 v = *(const float2*)(Gc + (size_t)s * 128);
            acc0.x += v.x; acc0.y += v.y;
        }
        float d = dinv[node];
        float ox = fmaxf(d * (acc0.x + acc1.x) + bias[o], 0.f);
        float oy = fmaxf(d * (acc0.y + acc1.y) + bias[o + 1], 0.f);
        *(float2*)(H + (size_t)node * 128 + o) = make_float2(ox, oy);
    } else {  // F == 64
        const float* __restrict__ Gc = G + lane;
        float acc0 = Gc[(size_t)node * 64];
        float acc1 = 0.f;
        int p = start;
        for (; p + 4 <= end; p += 4) {
            int s0 = csr[p + 0];
            int s1 = csr[p + 1];
            int s2 = csr[p + 2];
            int s3 = csr[p + 3];
            float v0 = Gc[(size_t)s0 * 64];
            float v1 = Gc[(size_t)s1 * 64];
            float v2 = Gc[(size_t)s2 * 64];
            float v3 = Gc[(size_t)s3 * 64];
            acc0 += v0; acc1 += v1; acc0 += v2; acc1 += v3;
        }
        for (; p < end; p++) acc0 += Gc[(size_t)csr[p] * 64];
        H[(size_t)node * 64 + lane] =
            fmaxf(dinv[node] * (acc0 + acc1) + bias[lane], 0.f);
    }
}

__device__ inline int lower_bound_i(const int* __restrict__ a, int n, int key) {
    int lo = 0, hi = n;
    while (lo < hi) {
        int mid = (lo + hi) >> 1;
        if (a[mid] < key) lo = mid + 1; else hi = mid;
    }
    return lo;
}

// Fused mean-pool + FC head. batch is SORTED, so graph g's nodes are the
// contiguous range [lower_bound(g), lower_bound(g+1)). One block per graph,
// 256 threads = 4 waves; wave w strides rows, lane = feature. No atomics.
__global__ __launch_bounds__(256) void pool_head(
        const float* __restrict__ H, const int* __restrict__ batch, int N,
        const float* __restrict__ Wf1, const float* __restrict__ bf1,
        const float* __restrict__ Wf2, const float* __restrict__ bf2,
        float* __restrict__ out) {
    __shared__ float red[4][64];
    __shared__ float pooled[64];
    __shared__ float f1[32];
    int g = blockIdx.x;
    int t = threadIdx.x;
    int wave = t >> 6, lane = t & 63;
    int lo = lower_bound_i(batch, N, g);
    int hi = lower_bound_i(batch, N, g + 1);
    float acc = 0.f;
    for (int i = lo + wave; i < hi; i += 4) acc += H[i * 64 + lane];
    red[wave][lane] = acc;
    __syncthreads();
    if (t < 64) {
        float c = fmaxf((float)(hi - lo), 1.0f);
        pooled[t] = (red[0][t] + red[1][t] + red[2][t] + red[3][t]) / c;
    }
    __syncthreads();
    if (t < 32) {
        float s = bf1[t];
        for (int k = 0; k < 64; k++) s += pooled[k] * Wf1[k * 32 + t];
        f1[t] = fmaxf(s, 0.f);
    }
    __syncthreads();
    if (t < 10) {
        float s = bf2[t];
        for (int k = 0; k < 32; k++) s += f1[k] * Wf2[k * 10 + t];
        out[g * 10 + t] = s;
    }
}

extern "C" void kernel_launch(void* const* d_in, const int* in_sizes, int n_in,
                              void* d_out, int out_size, void* d_ws, size_t ws_size,
                              hipStream_t stream) {
    const float* x    = (const float*)d_in[0];
    const int*   ei   = (const int*)d_in[1];   // [2,E] flat: [0..E)=src, [E..2E)=dst
    const int*   batch= (const int*)d_in[2];
    const float* W1 = (const float*)d_in[3];
    const float* b1 = (const float*)d_in[4];
    const float* W2 = (const float*)d_in[5];
    const float* b2 = (const float*)d_in[6];
    const float* W3 = (const float*)d_in[7];
    const float* b3 = (const float*)d_in[8];
    const float* Wf1 = (const float*)d_in[9];
    const float* bf1 = (const float*)d_in[10];
    const float* Wf2 = (const float*)d_in[11];
    const float* bf2 = (const float*)d_in[12];

    const int N = in_sizes[0] / 128;
    const int E = in_sizes[1] / 2;
    const int nb = (N + 255) / 256;   // scan blocks (<=1024 supported)

    // workspace layout
    char* w = (char*)d_ws;
    int*   off  = (int*)w;    w += align256((size_t)N * 4);
    float* dinv = (float*)w;  w += align256((size_t)N * 4);
    int*   part = (int*)w;    w += align256((size_t)1024 * 4);
    int*   csr  = (int*)w;    w += align256((size_t)E * 4);
    float* buf0 = (float*)w;  w += align256((size_t)N * 128 * 4);
    float* buf1 = (float*)w;  w += align256((size_t)N * 128 * 4);
    (void)ws_size; (void)n_in; (void)out_size;

    (void)hipMemsetAsync(off, 0, (size_t)N * 4, stream);

    int eb = (E + 255) / 256;
    count_edges<<<eb, 256, 0, stream>>>(ei + E, E, off);
    scan_part_sums<<<nb, 256, 0, stream>>>(off, N, part);
    scan_partials<<<1, 1024, 0, stream>>>(part, nb);
    scan_apply<<<nb, 256, 0, stream>>>(off, dinv, part, N);
    fill_csr<<<eb, 256, 0, stream>>>(ei, ei + E, E, off, csr);

    int aggb = (N * 64 + 255) / 256;
    // layer 1: x[ N,128 ] -> h1 (buf1)
    gemm_dinv<128><<<(N + 31) / 32, 256, 0, stream>>>(x, W1, dinv, buf0, N);
    aggregate<128><<<aggb, 256, 0, stream>>>(buf0, csr, off, dinv, b1, buf1, N);
    // layer 2
    gemm_dinv<128><<<(N + 31) / 32, 256, 0, stream>>>(buf1, W2, dinv, buf0, N);
    aggregate<128><<<aggb, 256, 0, stream>>>(buf0, csr, off, dinv, b2, buf1, N);
    // layer 3 (128 -> 64)
    gemm_dinv<64><<<(N + 63) / 64, 256, 0, stream>>>(buf1, W3, dinv, buf0, N);
    aggregate<64><<<aggb, 256, 0, stream>>>(buf0, csr, off, dinv, b3, buf1, N);

    pool_head<<<64, 256, 0, stream>>>(buf1, batch, N, Wf1, bf1, Wf2, bf2,
                                      (float*)d_out);
}

// Round 7
// 383.004 us; speedup vs baseline: 1.6623x; 1.1170x over previous
//
#include <hip/hip_runtime.h>

// GCN forward on MI355X.
// Pipeline per call (all on `stream`, graph-capture safe):
//   memset(counts) -> count in-degrees -> 3-phase multi-block scan
//   (partial sums -> scan partials -> apply; also emits dinv)
//   -> fill CSR (atomic cursor on offsets; offsets become END pointers)
//   -> per layer: [gemm: g = dinv .* (h @ W)] then [aggregate: CSR gather-sum
//      with 4-way MLP unroll, + self, * dinv, + bias, relu]
//   -> two-phase pool (2048-block partial reduce, then wave-per-graph head).
// Norm factorization: out[c] = dinv[c]*(sum_{src->c} g[src] + g[c]) + b,
// with g = dinv .* (h@W). No per-edge multiplies, no float atomics anywhere.
// R2: single-block scan was 124us -> multi-block scan.
// R5: XCD-slicing REGRESSED (split 128B lines across XCDs); reverted.
// R6: 4-way MLP unroll in aggregate: 637 -> 428us.
// R7: pool_head was 62us at 2.3% occupancy (64 blocks, latency-bound row
//     walk); split into pool_partial (64x32 blocks) + pool_head2 (wave/graph).

#define K_IN 128
#define PCH 32   // pooling chunks per graph

static inline size_t align256(size_t x) { return (x + 255) & ~(size_t)255; }

__global__ void count_edges(const int* __restrict__ col, int E, int* __restrict__ cnt) {
    int e = blockIdx.x * blockDim.x + threadIdx.x;
    if (e < E) atomicAdd(&cnt[col[e]], 1);
}

// Phase 1: per-block (256-elt chunk) sums of cnt.
__global__ __launch_bounds__(256) void scan_part_sums(const int* __restrict__ cnt,
                                                      int N, int* __restrict__ part) {
    __shared__ int red[256];
    int t = threadIdx.x;
    int i = blockIdx.x * 256 + t;
    red[t] = (i < N) ? cnt[i] : 0;
    __syncthreads();
    for (int s = 128; s > 0; s >>= 1) {
        if (t < s) red[t] += red[t + s];
        __syncthreads();
    }
    if (t == 0) part[blockIdx.x] = red[0];
}

// Phase 2: single block exclusive-scan of nb partials (nb <= 1024).
__global__ __launch_bounds__(1024) void scan_partials(int* __restrict__ part, int nb) {
    __shared__ int sh[1024];
    int t = threadIdx.x;
    int v = (t < nb) ? part[t] : 0;
    sh[t] = v;
    __syncthreads();
    int incl = v;
    for (int s = 1; s < 1024; s <<= 1) {
        int add = (t >= s) ? sh[t - s] : 0;
        __syncthreads();
        incl += add;
        sh[t] = incl;
        __syncthreads();
    }
    if (t < nb) part[t] = incl - v;
}

// Phase 3: block-local exclusive scan + block prefix; cnt->offsets in place,
// emits dinv[i] = rsqrt(deg_in + 1).
__global__ __launch_bounds__(256) void scan_apply(int* __restrict__ off,
                                                  float* __restrict__ dinv,
                                                  const int* __restrict__ part, int N) {
    __shared__ int sh[256];
    int t = threadIdx.x;
    int i = blockIdx.x * 256 + t;
    int c = (i < N) ? off[i] : 0;
    sh[t] = c;
    __syncthreads();
    int incl = c;
    for (int s = 1; s < 256; s <<= 1) {
        int add = (t >= s) ? sh[t - s] : 0;
        __syncthreads();
        incl += add;
        sh[t] = incl;
        __syncthreads();
    }
    if (i < N) {
        off[i] = part[blockIdx.x] + incl - c;
        dinv[i] = rsqrtf((float)(c + 1));
    }
}

// After this kernel, off[i] == end offset of node i (== start of node i+1).
__global__ void fill_csr(const int* __restrict__ rowi, const int* __restrict__ coli,
                         int E, int* __restrict__ off, int* __restrict__ csr) {
    int e = blockIdx.x * blockDim.x + threadIdx.x;
    if (e < E) {
        int c = coli[e];
        int p = atomicAdd(&off[c], 1);
        csr[p] = rowi[e];
    }
}

// G = dinv .* (X @ W).  X: [N,128], W: [128,COLS], G: [N,COLS]. fp32 LDS-tiled.
template <int COLS>
__global__ __launch_bounds__(256) void gemm_dinv(const float* __restrict__ X,
                                                 const float* __restrict__ W,
                                                 const float* __restrict__ dinv,
                                                 float* __restrict__ G, int N) {
    constexpr int CG = COLS / 4;       // col groups of 4
    constexpr int RG = 256 / CG;       // row groups
    constexpr int ROWS = RG * 4;       // rows per block (32 or 64)
    constexpr int BK = 64;
    constexpr int PAD = 4;             // keep 16B alignment for b128 reads
    __shared__ float Ws[BK][COLS];
    __shared__ float Xs[BK][ROWS + PAD];  // X tile transposed: Xs[k][r]

    int t = threadIdx.x;
    int rowBase = blockIdx.x * ROWS;
    float acc[4][4] = {};

    for (int kt = 0; kt < K_IN; kt += BK) {
        // stage W tile (coalesced float4)
        for (int i = t; i < BK * (COLS / 4); i += 256) {
            int c4 = i % (COLS / 4), k = i / (COLS / 4);
            float4 v = *(const float4*)(W + (kt + k) * COLS + c4 * 4);
            *(float4*)&Ws[k][c4 * 4] = v;
        }
        // stage X tile, transposed (coalesced float4 read, scalar LDS writes)
        for (int i = t; i < ROWS * (BK / 4); i += 256) {
            int k4 = i % (BK / 4), r = i / (BK / 4);
            int row = rowBase + r;
            float4 v = make_float4(0.f, 0.f, 0.f, 0.f);
            if (row < N) v = *(const float4*)(X + row * K_IN + kt + k4 * 4);
            Xs[k4 * 4 + 0][r] = v.x;
            Xs[k4 * 4 + 1][r] = v.y;
            Xs[k4 * 4 + 2][r] = v.z;
            Xs[k4 * 4 + 3][r] = v.w;
        }
        __syncthreads();
        int c0 = (t % CG) * 4, r0 = (t / CG) * 4;
#pragma unroll
        for (int k = 0; k < BK; k++) {
            float4 xv = *(const float4*)&Xs[k][r0];
            float4 wv = *(const float4*)&Ws[k][c0];
            acc[0][0] += xv.x * wv.x; acc[0][1] += xv.x * wv.y;
            acc[0][2] += xv.x * wv.z; acc[0][3] += xv.x * wv.w;
            acc[1][0] += xv.y * wv.x; acc[1][1] += xv.y * wv.y;
            acc[1][2] += xv.y * wv.z; acc[1][3] += xv.y * wv.w;
            acc[2][0] += xv.z * wv.x; acc[2][1] += xv.z * wv.y;
            acc[2][2] += xv.z * wv.z; acc[2][3] += xv.z * wv.w;
            acc[3][0] += xv.w * wv.x; acc[3][1] += xv.w * wv.y;
            acc[3][2] += xv.w * wv.z; acc[3][3] += xv.w * wv.w;
        }
        __syncthreads();
    }
    int c0 = (t % CG) * 4, r0 = (t / CG) * 4;
#pragma unroll
    for (int i = 0; i < 4; i++) {
        int row = rowBase + r0 + i;
        if (row < N) {
            float d = dinv[row];
            float4 o = make_float4(d * acc[i][0], d * acc[i][1],
                                   d * acc[i][2], d * acc[i][3]);
            *(float4*)(G + row * COLS + c0) = o;
        }
    }
}

// One wave per node, lane owns a float2 (F=128) or float (F=64) of the row.
// Edge loop unrolled x4: batch 4 csr index loads, then 4 independent row
// gathers in flight (MLP), accumulate into 2 partial sums.
// H[i] = relu(dinv[i]*(sum_{p} G[csr[p]] + G[i]) + bias)
template <int F>
__global__ void aggregate(const float* __restrict__ G, const int* __restrict__ csr,
                          const int* __restrict__ offEnd, const float* __restrict__ dinv,
                          const float* __restrict__ bias, float* __restrict__ H, int N) {
    int gid = blockIdx.x * blockDim.x + threadIdx.x;
    int node = gid >> 6;
    int lane = gid & 63;
    if (node >= N) return;
    int start = node ? offEnd[node - 1] : 0;
    int end = offEnd[node];
    if (F == 128) {
        int o = lane * 2;
        const float* __restrict__ Gc = G + o;
        float2 acc0 = *(const float2*)(Gc + (size_t)node * 128);  // self-loop
        float2 acc1 = make_float2(0.f, 0.f);
        int p = start;
        for (; p + 4 <= end; p += 4) {
            int s0 = csr[p + 0];
            int s1 = csr[p + 1];
            int s2 = csr[p + 2];
            int s3 = csr[p + 3];
            float2 v0 = *(const float2*)(Gc + (size_t)s0 * 128);
            float2 v1 = *(const float2*)(Gc + (size_t)s1 * 128);
            float2 v2 = *(const float2*)(Gc + (size_t)s2 * 128);
            float2 v3 = *(const float2*)(Gc + (size_t)s3 * 128);
            acc0.x += v0.x; acc0.y += v0.y;
            acc1.x += v1.x; acc1.y += v1.y;
            acc0.x += v2.x; acc0.y += v2.y;
            acc1.x += v3.x; acc1.y += v3.y;
        }
        for (; p < end; p++) {
            int s = csr[p];
            float2 v = *(const float2*)(Gc + (size_t)s * 128);
            acc0.x += v.x; acc0.y += v.y;
        }
        float d = dinv[node];
        float ox = fmaxf(d * (acc0.x + acc1.x) + bias[o], 0.f);
        float oy = fmaxf(d * (acc0.y + acc1.y) + bias[o + 1], 0.f);
        *(float2*)(H + (size_t)node * 128 + o) = make_float2(ox, oy);
    } else {  // F == 64
        const float* __restrict__ Gc = G + lane;
        float acc0 = Gc[(size_t)node * 64];
        float acc1 = 0.f;
        int p = start;
        for (; p + 4 <= end; p += 4) {
            int s0 = csr[p + 0];
            int s1 = csr[p + 1];
            int s2 = csr[p + 2];
            int s3 = csr[p + 3];
            float v0 = Gc[(size_t)s0 * 64];
            float v1 = Gc[(size_t)s1 * 64];
            float v2 = Gc[(size_t)s2 * 64];
            float v3 = Gc[(size_t)s3 * 64];
            acc0 += v0; acc1 += v1; acc0 += v2; acc1 += v3;
        }
        for (; p < end; p++) acc0 += Gc[(size_t)csr[p] * 64];
        H[(size_t)node * 64 + lane] =
            fmaxf(dinv[node] * (acc0 + acc1) + bias[lane], 0.f);
    }
}

__device__ inline int lower_bound_i(const int* __restrict__ a, int n, int key) {
    int lo = 0, hi = n;
    while (lo < hi) {
        int mid = (lo + hi) >> 1;
        if (a[mid] < key) lo = mid + 1; else hi = mid;
    }
    return lo;
}

// Pool phase 1: grid = 64 graphs x PCH chunks. Block = 256 = 4 waves; the
// PCH*4 waves of one graph take interleaved rows (consecutive rows in flight
// across blocks). Deterministic fixed-order partial -> ppart[g*PCH+c][64].
__global__ __launch_bounds__(256) void pool_partial(
        const float* __restrict__ H, const int* __restrict__ batch, int N,
        float* __restrict__ ppart) {
    __shared__ float red[4][64];
    int g = blockIdx.x / PCH;
    int c = blockIdx.x % PCH;
    int t = threadIdx.x;
    int wave = t >> 6, lane = t & 63;
    int lo = lower_bound_i(batch, N, g);
    int hi = lower_bound_i(batch, N, g + 1);
    float acc = 0.f;
    for (int i = lo + c * 4 + wave; i < hi; i += PCH * 4)
        acc += H[(size_t)i * 64 + lane];
    red[wave][lane] = acc;
    __syncthreads();
    if (t < 64)
        ppart[((size_t)g * PCH + c) * 64 + t] =
            red[0][t] + red[1][t] + red[2][t] + red[3][t];
}

// Pool phase 2 + FC head: one wave per graph; lane t sums the PCH partials
// for feature t (coalesced across lanes), then tiny FC in LDS.
__global__ __launch_bounds__(64) void pool_head2(
        const float* __restrict__ ppart, const int* __restrict__ batch, int N,
        const float* __restrict__ Wf1, const float* __restrict__ bf1,
        const float* __restrict__ Wf2, const float* __restrict__ bf2,
        float* __restrict__ out) {
    __shared__ float pooled[64];
    __shared__ float f1[32];
    int g = blockIdx.x;
    int t = threadIdx.x;
    int lo = lower_bound_i(batch, N, g);
    int hi = lower_bound_i(batch, N, g + 1);
    float s = 0.f;
    for (int c = 0; c < PCH; c++) s += ppart[((size_t)g * PCH + c) * 64 + t];
    pooled[t] = s / fmaxf((float)(hi - lo), 1.0f);
    __syncthreads();
    if (t < 32) {
        float v = bf1[t];
        for (int k = 0; k < 64; k++) v += pooled[k] * Wf1[k * 32 + t];
        f1[t] = fmaxf(v, 0.f);
    }
    __syncthreads();
    if (t < 10) {
        float v = bf2[t];
        for (int k = 0; k < 32; k++) v += f1[k] * Wf2[k * 10 + t];
        out[g * 10 + t] = v;
    }
}

extern "C" void kernel_launch(void* const* d_in, const int* in_sizes, int n_in,
                              void* d_out, int out_size, void* d_ws, size_t ws_size,
                              hipStream_t stream) {
    const float* x    = (const float*)d_in[0];
    const int*   ei   = (const int*)d_in[1];   // [2,E] flat: [0..E)=src, [E..2E)=dst
    const int*   batch= (const int*)d_in[2];
    const float* W1 = (const float*)d_in[3];
    const float* b1 = (const float*)d_in[4];
    const float* W2 = (const float*)d_in[5];
    const float* b2 = (const float*)d_in[6];
    const float* W3 = (const float*)d_in[7];
    const float* b3 = (const float*)d_in[8];
    const float* Wf1 = (const float*)d_in[9];
    const float* bf1 = (const float*)d_in[10];
    const float* Wf2 = (const float*)d_in[11];
    const float* bf2 = (const float*)d_in[12];

    const int N = in_sizes[0] / 128;
    const int E = in_sizes[1] / 2;
    const int nb = (N + 255) / 256;   // scan blocks (<=1024 supported)

    // workspace layout
    char* w = (char*)d_ws;
    int*   off  = (int*)w;    w += align256((size_t)N * 4);
    float* dinv = (float*)w;  w += align256((size_t)N * 4);
    int*   part = (int*)w;    w += align256((size_t)1024 * 4);
    int*   csr  = (int*)w;    w += align256((size_t)E * 4);
    float* ppart= (float*)w;  w += align256((size_t)64 * PCH * 64 * 4);
    float* buf0 = (float*)w;  w += align256((size_t)N * 128 * 4);
    float* buf1 = (float*)w;  w += align256((size_t)N * 128 * 4);
    (void)ws_size; (void)n_in; (void)out_size;

    (void)hipMemsetAsync(off, 0, (size_t)N * 4, stream);

    int eb = (E + 255) / 256;
    count_edges<<<eb, 256, 0, stream>>>(ei + E, E, off);
    scan_part_sums<<<nb, 256, 0, stream>>>(off, N, part);
    scan_partials<<<1, 1024, 0, stream>>>(part, nb);
    scan_apply<<<nb, 256, 0, stream>>>(off, dinv, part, N);
    fill_csr<<<eb, 256, 0, stream>>>(ei, ei + E, E, off, csr);

    int aggb = (N * 64 + 255) / 256;
    // layer 1: x[ N,128 ] -> h1 (buf1)
    gemm_dinv<128><<<(N + 31) / 32, 256, 0, stream>>>(x, W1, dinv, buf0, N);
    aggregate<128><<<aggb, 256, 0, stream>>>(buf0, csr, off, dinv, b1, buf1, N);
    // layer 2
    gemm_dinv<128><<<(N + 31) / 32, 256, 0, stream>>>(buf1, W2, dinv, buf0, N);
    aggregate<128><<<aggb, 256, 0, stream>>>(buf0, csr, off, dinv, b2, buf1, N);
    // layer 3 (128 -> 64)
    gemm_dinv<64><<<(N + 63) / 64, 256, 0, stream>>>(buf1, W3, dinv, buf0, N);
    aggregate<64><<<aggb, 256, 0, stream>>>(buf0, csr, off, dinv, b3, buf1, N);

    pool_partial<<<64 * PCH, 256, 0, stream>>>(buf1, batch, N, ppart);
    pool_head2<<<64, 64, 0, stream>>>(ppart, batch, N, Wf1, bf1, Wf2, bf2,
                                      (float*)d_out);
}